// Round 8
// baseline (1445.201 us; speedup 1.0000x reference)
//
#include <hip/hip_runtime.h>
#include <hip/hip_bf16.h>
#include <stdint.h>

// SimTransformer — fp32 I/O, fp64 mask chain (absmax 0.031, stable).
// R8: qk_mfma rework per R7 counters (2.2e7 LDS-atomic conflicts, 844 MB
// fetch, 23% occupancy): A-frags in VGPRs (no Qs LDS; LDS 104->37 KB,
// 2 blocks/CU), ballot-aggregated list appends (1 atomic per row-group),
// XCD-aware block swizzle (same-batch blocks share an XCD L2).

typedef __bf16 bf16;
typedef __bf16 bf16x8 __attribute__((ext_vector_type(8)));
typedef float f4 __attribute__((ext_vector_type(4)));

#define CAP 768
#define BAND 0.0015f
#define BCAPC 512

// ---------------------------------------------------------------------------
// K1: Q[n,e] = sum_d X[n,d]*W[e,d] in fp64. 64x64 tile, 256 thr (proven).
// ---------------------------------------------------------------------------
__global__ __launch_bounds__(256) void proj_f64(const float* __restrict__ X,
                                                const float* __restrict__ W,
                                                double* __restrict__ Q) {
    __shared__ double As[64][66];
    __shared__ double Bs[64][66];
    const int t = threadIdx.x, tn = t >> 4, te = t & 15;
    const int n0 = blockIdx.x * 64, e0 = blockIdx.y * 64;
    double acc[4][4] = {};
    for (int p = 0; p < 8; ++p) {
        __syncthreads();
        for (int q = 0; q < 16; ++q) {
            int id = q * 256 + t, r = id >> 6, c = id & 63;
            As[r][c] = (double)X[(size_t)(n0 + r) * 512 + p * 64 + c];
            Bs[r][c] = (double)W[(size_t)(e0 + r) * 512 + p * 64 + c];
        }
        __syncthreads();
        for (int kk = 0; kk < 64; ++kk) {
            double av[4], bv[4];
            for (int i = 0; i < 4; ++i) av[i] = As[tn + 16 * i][kk];
            for (int j = 0; j < 4; ++j) bv[j] = Bs[te + 16 * j][kk];
            for (int i = 0; i < 4; ++i)
                for (int j = 0; j < 4; ++j) acc[i][j] += av[i] * bv[j];
        }
    }
    for (int i = 0; i < 4; ++i)
        for (int j = 0; j < 4; ++j)
            Q[(size_t)(n0 + tn + 16 * i) * 512 + e0 + te + 16 * j] = acc[i][j];
}

// ---------------------------------------------------------------------------
// K1b: VT[b][e][m] = (X Wv^T)[m,e], fp32 accum, bf16 out, LDS-transposed.
// ---------------------------------------------------------------------------
__global__ __launch_bounds__(256) void proj_v(const float* __restrict__ X,
                                              const float* __restrict__ W,
                                              bf16* __restrict__ VT) {
    __shared__ float As[64][132];
    __shared__ float Bs[64][132];
    __shared__ bf16 Tt[64][72];
    const int t = threadIdx.x, tn = t >> 4, te = t & 15;
    const int n0 = blockIdx.x * 64, e0 = blockIdx.y * 64;
    f4 acc[4][4] = {};
    for (int p = 0; p < 4; ++p) {
        __syncthreads();
        for (int q = 0; q < 8; ++q) {
            int id = q * 256 + t, r = id >> 5, c = (id & 31) * 4;
            *(f4*)&As[r][c] = *(const f4*)&X[(size_t)(n0 + r) * 512 + p * 128 + c];
            *(f4*)&Bs[r][c] = *(const f4*)&W[(size_t)(e0 + r) * 512 + p * 128 + c];
        }
        __syncthreads();
        for (int kk = 0; kk < 32; ++kk) {
            f4 av[4], bv[4];
            for (int i = 0; i < 4; ++i) av[i] = *(const f4*)&As[tn + 16 * i][kk * 4];
            for (int j = 0; j < 4; ++j) bv[j] = *(const f4*)&Bs[te + 16 * j][kk * 4];
            for (int i = 0; i < 4; ++i)
                for (int j = 0; j < 4; ++j) acc[i][j] += av[i] * bv[j];
        }
    }
    for (int i = 0; i < 4; ++i)
        for (int j = 0; j < 4; ++j) {
            f4 a = acc[i][j];
            Tt[te + 16 * j][tn + 16 * i] = (bf16)((a.x + a.y) + (a.z + a.w));
        }
    __syncthreads();
    const int b = n0 >> 12, ml = n0 & 4095;
    for (int i2 = 0; i2 < 2; ++i2) {
        int id = i2 * 256 + t, er = id >> 3, g = (id & 7) * 8;
        *(bf16x8*)&VT[((size_t)b * 512 + e0 + er) * 4096 + ml + g] =
            *(bf16x8*)&Tt[er][g];
    }
}

// ---------------------------------------------------------------------------
// K2: wave-per-row fp64 normalize; writes qn (fp64) and qnb (bf16). (proven)
// ---------------------------------------------------------------------------
__global__ __launch_bounds__(256) void norm_q(double* __restrict__ Q,
                                              bf16* __restrict__ QB) {
    const int wave = threadIdx.x >> 6, lane = threadIdx.x & 63;
    const int row = blockIdx.x * 4 + wave;
    double* q = Q + (size_t)row * 512;
    bf16* qb = QB + (size_t)row * 512;
    double x[8];
    double s = 0.0;
    for (int j = 0; j < 8; ++j) { x[j] = q[lane * 8 + j]; s += x[j] * x[j]; }
    for (int off = 1; off < 64; off <<= 1) s += __shfl_xor(s, off);
    double nm = fmax(sqrt(s), 1e-12);
    for (int j = 0; j < 8; ++j) {
        double qq = x[j] / nm;
        q[lane * 8 + j] = qq;
        qb[lane * 8 + j] = (bf16)(float)qq;
    }
}

// ---------------------------------------------------------------------------
// K3 v2: bf16-MFMA prefilter + inline fp64 verify.
// grid 256; XCD swizzle: b=(blk&7)>>1 so each XCD's 32 blocks share a batch.
// A-fragments resident in VGPRs (64/lane); QMs staged per 128-k panel.
// Ballot-aggregated appends: one LDS atomic per 16-lane row-group.
// ---------------------------------------------------------------------------
__global__ __launch_bounds__(512, 4) void qk_mfma(const double* __restrict__ QN,
                                                  const bf16* __restrict__ QNB,
                                                  uint32_t* __restrict__ counts,
                                                  uint16_t* __restrict__ idxs,
                                                  bf16* __restrict__ vals) {
    __shared__ bf16 QMs[128][136];     // 34,816 B
    __shared__ int cnt[64];
    __shared__ int bcnt;
    __shared__ uint32_t blist[BCAPC];  // 2,048 B  (total ~37 KB -> 2 blk/CU)

    const int t = threadIdx.x;
    const int wave = t >> 6, lane = t & 63;
    const int ln16 = lane & 15, hi4 = lane >> 4;
    const int rg = wave & 3, ch = wave >> 2;
    const int blk = blockIdx.x;
    const int b = (blk & 7) >> 1;                    // XCD pair per batch
    const int n0 = ((blk >> 3) | ((blk & 1) << 5)) * 64;
    const size_t nb = (size_t)b * 4096;
    const bf16* qnb = QNB + nb * 512;
    const double* qnf = QN + nb * 512;

    // resident A-fragments: rows n0+rg*16+ln16, 16 k-chunks of 32
    bf16x8 areg[16];
    {
        const bf16* ar = qnb + (size_t)(n0 + rg * 16 + ln16) * 512 + hi4 * 8;
#pragma unroll
        for (int c = 0; c < 16; ++c) areg[c] = *(const bf16x8*)&ar[c * 32];
    }
    if (t < 64) cnt[t] = 0;
    if (t == 0) bcnt = 0;

    const int rl = rg * 16 + hi4 * 4;

    for (int m0 = 0; m0 < 4096; m0 += 128) {
        f4 S[4] = {};
#pragma unroll
        for (int kp = 0; kp < 4; ++kp) {
            __syncthreads();           // QMs safe (also orders bcnt reset/init)
#pragma unroll
            for (int i = 0; i < 4; ++i) {
                int id = i * 512 + t, r = id >> 4, g = (id & 15) * 8;
                *(bf16x8*)&QMs[r][g] =
                    *(const bf16x8*)&qnb[(size_t)(m0 + r) * 512 + kp * 128 + g];
            }
            __syncthreads();
#pragma unroll
            for (int j = 0; j < 4; ++j) {
                bf16x8 a = areg[kp * 4 + j];
#pragma unroll
                for (int tt = 0; tt < 4; ++tt) {
                    bf16x8 bb = *(const bf16x8*)&QMs[ch * 64 + tt * 16 + ln16][j * 32 + hi4 * 8];
                    S[tt] = __builtin_amdgcn_mfma_f32_16x16x32_bf16(a, bb, S[tt], 0, 0, 0);
                }
            }
        }
        // threshold: ballot-aggregated accept / borderline appends
        for (int tt = 0; tt < 4; ++tt) {
            int m = m0 + ch * 64 + tt * 16 + ln16;
            for (int i = 0; i < 4; ++i) {
                float cs = S[tt][i];
                int row = rl + i;
                bool ap = cs > 0.1f + BAND;
                unsigned long long mk = __ballot(ap);
                unsigned gm = (unsigned)((mk >> (hi4 * 16)) & 0xFFFFull);
                if (gm) {
                    int ldr = __ffs(gm) - 1;
                    int base = 0;
                    if (ln16 == ldr) base = atomicAdd(&cnt[row], __popc(gm));
                    base = __shfl(base, hi4 * 16 + ldr);
                    if (ap) {
                        int pos = base + __popc(gm & ((1u << ln16) - 1u));
                        if (pos < CAP) {
                            size_t o = (nb + n0 + row) * CAP + pos;
                            idxs[o] = (uint16_t)m;
                            vals[o] = (bf16)cs;
                        }
                    }
                }
                bool bp = !ap && cs > 0.1f - BAND;
                unsigned long long bm = __ballot(bp);
                if (bm) {
                    int nset = __popcll(bm);
                    int lb = __ffsll(bm) - 1;
                    int bbase = 0;
                    if (lane == lb) bbase = atomicAdd(&bcnt, nset);
                    bbase = __shfl(bbase, lb);
                    if (bp) {
                        int pos = bbase + __popcll(bm & ((1ull << lane) - 1ull));
                        if (pos < BCAPC)
                            blist[pos] = ((uint32_t)row << 12) | (uint32_t)m;
                    }
                }
            }
        }
        __syncthreads();               // blist complete
        int nbd = bcnt; if (nbd > BCAPC) nbd = BCAPC;
        for (int p = wave; p < nbd; p += 8) {   // wave-parallel fp64 dots
            uint32_t pk = blist[p];
            int row = (int)(pk >> 12), m = (int)(pk & 4095);
            const double* qa = qnf + (size_t)(n0 + row) * 512;
            const double* qc = qnf + (size_t)m * 512;
            double s = 0.0;
            for (int j = 0; j < 8; ++j) s += qa[lane * 8 + j] * qc[lane * 8 + j];
            for (int off = 1; off < 64; off <<= 1) s += __shfl_xor(s, off);
            if (lane == 0 && s > 0.1) {
                int pos = atomicAdd(&cnt[row], 1);
                if (pos < CAP) {
                    size_t o = (nb + n0 + row) * CAP + pos;
                    idxs[o] = (uint16_t)m;
                    vals[o] = (bf16)(float)s;
                }
            }
        }
        __syncthreads();               // verify appends done
        if (t == 0) bcnt = 0;          // ordered by next chunk's staging barrier
    }
    __syncthreads();
    if (t < 64) {
        int c = cnt[t];
        counts[nb + n0 + t] = (uint32_t)(c > CAP ? CAP : c);
    }
}

// ---------------------------------------------------------------------------
// K4: MFMA PV + fused LayerNorm (unchanged from R7, proven).
// ---------------------------------------------------------------------------
__global__ __launch_bounds__(512) void pv_mfma(const bf16* __restrict__ VT,
                                               const uint32_t* __restrict__ counts,
                                               const uint16_t* __restrict__ idxs,
                                               const bf16* __restrict__ vals,
                                               const float* __restrict__ gamma,
                                               const float* __restrict__ beta,
                                               float* __restrict__ Out) {
    __shared__ bf16 Wsm[32][136];
    __shared__ bf16 Vts[128][136];
    __shared__ int cur[32];
    __shared__ float red[4][32][2];

    const int t = threadIdx.x;
    const int wave = t >> 6, lane = t & 63;
    const int ln16 = lane & 15, hi4 = lane >> 4;
    const int rg = wave & 1, et = wave >> 1;
    const int b = blockIdx.x >> 7;
    const int n0 = (blockIdx.x & 127) * 32;
    const size_t nb = (size_t)b * 4096;
    const bf16* vtb = VT + (size_t)b * 512 * 4096;

    int myc = 0;
    if (t < 32) {
        int c = (int)counts[nb + n0 + t];
        myc = c < 0 ? 0 : (c > CAP ? CAP : c);
        cur[t] = 0;
    }

    f4 O[8] = {};

    for (int m0 = 0; m0 < 4096; m0 += 128) {
        __syncthreads();
        if (t < 32) {
            uint32_t* wz = (uint32_t*)&Wsm[t][0];
            for (int j = 0; j < 68; ++j) wz[j] = 0;
            const size_t base = (nb + n0 + t) * CAP;
            int cu = cur[t];
            while (cu < myc) {
                int mi = (int)(idxs[base + cu] & 4095);
                if (mi >= m0 + 128) break;
                int lo = mi - m0;
                if (lo >= 0) Wsm[t][lo] = vals[base + cu];
                ++cu;
            }
            cur[t] = cu;
        }
        __syncthreads();
        for (int cc = 0; cc < 4; ++cc) {
            for (int i = 0; i < 4; ++i) {
                int id = i * 512 + t, r = id >> 4, g = (id & 15) * 8;
                *(bf16x8*)&Vts[r][g] =
                    *(const bf16x8*)&vtb[(size_t)(cc * 128 + r) * 4096 + m0 + g];
            }
            __syncthreads();
            for (int kk = 0; kk < 4; ++kk) {
                bf16x8 aw = *(const bf16x8*)&Wsm[rg * 16 + ln16][kk * 32 + hi4 * 8];
                for (int s2 = 0; s2 < 2; ++s2) {
                    bf16x8 bv = *(const bf16x8*)&Vts[et * 32 + s2 * 16 + ln16][kk * 32 + hi4 * 8];
                    O[cc * 2 + s2] = __builtin_amdgcn_mfma_f32_16x16x32_bf16(
                        aw, bv, O[cc * 2 + s2], 0, 0, 0);
                }
            }
            __syncthreads();
        }
    }

    const int rloc = rg * 16 + hi4 * 4;
    float ps[4] = {0, 0, 0, 0}, pq[4] = {0, 0, 0, 0};
    for (int idx = 0; idx < 8; ++idx)
        for (int i = 0; i < 4; ++i) {
            float v = O[idx][i]; ps[i] += v; pq[i] += v * v;
        }
    for (int off = 1; off < 16; off <<= 1)
        for (int i = 0; i < 4; ++i) {
            ps[i] += __shfl_xor(ps[i], off);
            pq[i] += __shfl_xor(pq[i], off);
        }
    if (ln16 == 0)
        for (int i = 0; i < 4; ++i) {
            red[et][rloc + i][0] = ps[i];
            red[et][rloc + i][1] = pq[i];
        }
    __syncthreads();
    float mu[4], rs[4];
    for (int i = 0; i < 4; ++i) {
        float s = red[0][rloc + i][0] + red[1][rloc + i][0] +
                  red[2][rloc + i][0] + red[3][rloc + i][0];
        float q2 = red[0][rloc + i][1] + red[1][rloc + i][1] +
                   red[2][rloc + i][1] + red[3][rloc + i][1];
        mu[i] = s * (1.0f / 512.0f);
        float var = q2 * (1.0f / 512.0f) - mu[i] * mu[i];
        rs[i] = rsqrtf(var + 1e-5f);
    }
    for (int cc = 0; cc < 4; ++cc)
        for (int s2 = 0; s2 < 2; ++s2) {
            int col = cc * 128 + et * 32 + s2 * 16 + ln16;
            float g = gamma[col], be = beta[col];
            for (int i = 0; i < 4; ++i) {
                float y = (O[cc * 2 + s2][i] - mu[i]) * rs[i] * g + be;
                Out[(nb + n0 + rloc + i) * 512 + col] = y;
            }
        }
}

// ---------------------------------------------------------------------------
extern "C" void kernel_launch(void* const* d_in, const int* in_sizes, int n_in,
                              void* d_out, int out_size, void* d_ws, size_t ws_size,
                              hipStream_t stream) {
    const float* x     = (const float*)d_in[0];
    const float* wqk   = (const float*)d_in[1];
    const float* wv    = (const float*)d_in[2];
    const float* gamma = (const float*)d_in[3];
    const float* beta  = (const float*)d_in[4];
    float* out = (float*)d_out;

    char* ws = (char*)d_ws;
    double*   qn     = (double*)ws;                          // 64 MiB
    bf16*     qnb    = (bf16*)(ws + 67108864);               // 16 MiB
    bf16*     vt     = (bf16*)(ws + 83886080);               // 16 MiB
    uint32_t* counts = (uint32_t*)(ws + 100663296);          // 64 KiB
    uint16_t* idxs   = (uint16_t*)(ws + 100728832);          // 24 MiB
    bf16*     vals   = (bf16*)(ws + 125894656);              // 24 MiB
    const size_t need = 151060480;  // == R2-proven ws_size lower bound
    if (ws_size < need) return;

    proj_f64<<<dim3(256, 8), 256, 0, stream>>>(x, wqk, qn);
    proj_v<<<dim3(256, 8), 256, 0, stream>>>(x, wv, vt);
    norm_q<<<4096, 256, 0, stream>>>(qn, qnb);
    qk_mfma<<<256, 512, 0, stream>>>(qn, qnb, counts, idxs, vals);
    pv_mfma<<<512, 512, 0, stream>>>(vt, counts, idxs, vals, gamma, beta, out);
}